// Round 2
// baseline (10999.654 us; speedup 1.0000x reference)
//
#include <hip/hip_runtime.h>
#include <cstdint>

#define B_ 32
#define L_ 512
#define G4_ 2048

typedef __bf16          bf16x8 __attribute__((ext_vector_type(8)));
typedef float           f32x4  __attribute__((ext_vector_type(4)));
typedef unsigned short  u16x8  __attribute__((ext_vector_type(8)));

__device__ __forceinline__ unsigned short f2bf(float v) {
  unsigned int u = __float_as_uint(v);
  unsigned int r = u + 0x7fffu + ((u >> 16) & 1u);   // RNE
  return (unsigned short)(r >> 16);
}
__device__ __forceinline__ float bf2f(unsigned short u) {
  return __uint_as_float(((unsigned int)u) << 16);
}
__device__ __forceinline__ float sigf(float x) { return 1.0f / (1.0f + __expf(-x)); }
__device__ __forceinline__ float tanhf_(float x) { return 1.0f - 2.0f / (__expf(2.0f * x) + 1.0f); }

// ---------- sentinel (ws too small): d_out = 1.0 everywhere ----------
__global__ __launch_bounds__(256) void k_fill(float* o, long n, float v) {
  for (long i = (long)blockIdx.x * 256 + threadIdx.x; i < n; i += (long)gridDim.x * 256) o[i] = v;
}

// ---------- fp32 -> bf16 flat convert ----------
__global__ __launch_bounds__(256) void k_cvt(const float* __restrict__ in,
                                             unsigned short* __restrict__ out, long n) {
  long i = ((long)blockIdx.x * 256 + threadIdx.x) * 8;
  if (i >= n) return;
  const float4* p = (const float4*)(in + i);
  float4 a = p[0], b = p[1];
  u16x8 o;
  o[0] = f2bf(a.x); o[1] = f2bf(a.y); o[2] = f2bf(a.z); o[3] = f2bf(a.w);
  o[4] = f2bf(b.x); o[5] = f2bf(b.y); o[6] = f2bf(b.z); o[7] = f2bf(b.w);
  *(u16x8*)(out + i) = o;
}

// ---------- pack [w_ih | w_hh] -> wcat[2048][1024] bf16 ----------
__global__ __launch_bounds__(256) void k_pack_w(const float* __restrict__ wih,
                                                const float* __restrict__ whh,
                                                unsigned short* __restrict__ wcat) {
  long i = ((long)blockIdx.x * 256 + threadIdx.x) * 8;   // exact grid: 2048*1024/8/256
  int row = (int)(i >> 10), col = (int)(i & 1023);
  const float* src = (col < 512) ? (wih + (long)row * 512 + col)
                                 : (whh + (long)row * 512 + (col - 512));
  const float4* p = (const float4*)src;
  float4 a = p[0], b = p[1];
  u16x8 o;
  o[0] = f2bf(a.x); o[1] = f2bf(a.y); o[2] = f2bf(a.z); o[3] = f2bf(a.w);
  o[4] = f2bf(b.x); o[5] = f2bf(b.y); o[6] = f2bf(b.z); o[7] = f2bf(b.w);
  *(u16x8*)(wcat + i) = o;
}

// ---------- persistent LSTM recurrence, fused Wx+Wh ----------
// 96 blocks = 6 row-groups (layer l, batch-half b0; 16 seqs) x 16 col-chunks (32 units).
// Per block: W chunk [128 gate-rows][1024] bf16 in registers (32 frags = 128 VGPR/lane).
// Per step: [x_t | h_{t-1}] staged to LDS [16][1024] (XOR-swizzled), 32-frag MFMA,
// gate math (c in a register per thread), h stored bf16 via device-scope atomics,
// cross-block sync via release/acquire flags. x_t prefetched 1 step ahead.
struct LBias { const float* bi[3]; const float* bh[3]; };

__global__ __launch_bounds__(512, 2) void lstm_rec(
    const unsigned short* __restrict__ wcat,  // [3][2048][1024]
    const unsigned short* __restrict__ xs,    // [96][512][512]
    LBias bb,
    unsigned short* __restrict__ hout,        // [96][512][512]
    int* __restrict__ flags)                  // [6][16]
{
  const int r8 = blockIdx.x & 7;              // XCD-affine: one row-group per XCD slot
  if (r8 >= 6) return;
  const int rg = r8, cc = blockIdx.x >> 3;    // cc in [0,16)
  const int l = rg >> 1, b0 = (rg & 1) * 16;
  const int tid = threadIdx.x, lane = tid & 63, wv = tid >> 6;

  __shared__ unsigned short sXH[16 * 1024];   // [16 seqs][x(512)|h(512)] swizzled, 32KB
  __shared__ float sD[128 * 17];              // gate preacts [128][16] padded
  __shared__ float sBias[128];

  if (tid < 128) {
    int grow = (tid >> 5) * 512 + cc * 32 + (tid & 31);
    sBias[tid] = bb.bi[l][grow] + bb.bh[l][grow];
  }

  bf16x8 af[32];                              // W chunk: 128 VGPR
  {
    int m = wv * 16 + (lane & 15);
    int grow = (m >> 5) * 512 + cc * 32 + (m & 31);
    const unsigned short* Wp = wcat + ((long)l * G4_ + grow) * 1024 + ((lane >> 4) << 3);
#pragma unroll
    for (int kf = 0; kf < 32; ++kf) af[kf] = *(const bf16x8*)(Wp + kf * 32);
  }

  const int sx = tid >> 5;                    // seq 0..15
  const int cxb = (tid & 31) << 5;            // byte offset of 32B chunk in 1024B half
  u16x8 xr0, xr1;                             // x prefetch regs
  {
    const unsigned short* p = xs + (((long)(l * B_ + b0 + sx)) * L_ + 0) * 512 + ((tid & 31) << 4);
    xr0 = *(const u16x8*)p;
    xr1 = *(const u16x8*)(p + 8);
  }
  const int fbase = rg * 16;
  const int u = tid & 31, sq = tid >> 5;
  float creg = 0.f;
  __syncthreads();

  for (int t = 0; t < L_; ++t) {
    // stage x(t) (prefetched) into x-half of sXH
    {
      int rb = sx << 11, sw = (sx & 7) << 4;
      *(u16x8*)((char*)sXH + ((rb + cxb) ^ sw))      = xr0;
      *(u16x8*)((char*)sXH + ((rb + cxb + 16) ^ sw)) = xr1;
    }
    // issue x(t+1) prefetch (consumed next iter -> latency hidden)
    if (t + 1 < L_) {
      const unsigned short* p = xs + (((long)(l * B_ + b0 + sx)) * L_ + (t + 1)) * 512 + ((tid & 31) << 4);
      xr0 = *(const u16x8*)p;
      xr1 = *(const u16x8*)(p + 8);
    }
    // stage h(t-1) into h-half
    if (t > 0) {
      if (tid < 16) {
        while (__hip_atomic_load(&flags[fbase + tid], __ATOMIC_ACQUIRE,
                                 __HIP_MEMORY_SCOPE_AGENT) < t)
          __builtin_amdgcn_s_sleep(2);
      }
      __syncthreads();
      const unsigned int* hsrc =
          (const unsigned int*)(hout + (((long)(l * B_ + b0 + sx)) * L_ + (t - 1)) * 512) +
          ((tid & 31) << 3);
      unsigned int hv[8];
#pragma unroll
      for (int j = 0; j < 8; ++j)
        hv[j] = __hip_atomic_load(hsrc + j, __ATOMIC_RELAXED, __HIP_MEMORY_SCOPE_AGENT);
      u16x8 ha, hb;
#pragma unroll
      for (int j = 0; j < 4; ++j) {
        ha[2 * j] = (unsigned short)(hv[j] & 0xffffu);
        ha[2 * j + 1] = (unsigned short)(hv[j] >> 16);
        hb[2 * j] = (unsigned short)(hv[4 + j] & 0xffffu);
        hb[2 * j + 1] = (unsigned short)(hv[4 + j] >> 16);
      }
      int rb = sx << 11, sw = (sx & 7) << 4;
      int o0 = rb + 1024 + cxb;
      *(u16x8*)((char*)sXH + (o0 ^ sw))        = ha;
      *(u16x8*)((char*)sXH + ((o0 + 16) ^ sw)) = hb;
    } else {
      u16x8 z = (u16x8){0, 0, 0, 0, 0, 0, 0, 0};
      int rb = sx << 11, sw = (sx & 7) << 4;
      int o0 = rb + 1024 + cxb;
      *(u16x8*)((char*)sXH + (o0 ^ sw))        = z;
      *(u16x8*)((char*)sXH + ((o0 + 16) ^ sw)) = z;
    }
    __syncthreads();
    // preact = W · [x;h]  (K=1024, 32 MFMA)
    f32x4 acc = (f32x4){0.f, 0.f, 0.f, 0.f};
    {
      int srow = lane & 15;
      int rb = srow << 11, sw = (srow & 7) << 4;
      int kob = (lane >> 4) << 4;
#pragma unroll
      for (int kf = 0; kf < 32; ++kf) {
        bf16x8 bv = *(const bf16x8*)((const char*)sXH + ((rb + kf * 64 + kob) ^ sw));
        acc = __builtin_amdgcn_mfma_f32_16x16x32_bf16(af[kf], bv, acc, 0, 0, 0);
      }
    }
    {
      int mb = wv * 16 + ((lane >> 4) << 2);
      int scn = lane & 15;
#pragma unroll
      for (int r = 0; r < 4; ++r) sD[(mb + r) * 17 + scn] = acc[r] + sBias[mb + r];
    }
    __syncthreads();
    // gates: thread owns cell (sq, u); c lives in a register
    {
      float Pi = sD[(u) * 17 + sq];
      float Pf = sD[(32 + u) * 17 + sq];
      float Pg = sD[(64 + u) * 17 + sq];
      float Po = sD[(96 + u) * 17 + sq];
      float iv = sigf(Pi), fv = sigf(Pf), gv = tanhf_(Pg), ov = sigf(Po);
      creg = fv * creg + iv * gv;
      float h = ov * tanhf_(creg);
      unsigned int hb16 = (unsigned int)f2bf(h);
      unsigned int other = (unsigned int)__shfl_xor((int)hb16, 1);
      if ((tid & 1) == 0) {
        unsigned int pk = hb16 | (other << 16);
        unsigned int* dst =
            (unsigned int*)(hout + (((long)(l * B_ + b0 + sq)) * L_ + t) * 512 + cc * 32 + u);
        __hip_atomic_store(dst, pk, __ATOMIC_RELAXED, __HIP_MEMORY_SCOPE_AGENT);
      }
    }
    __threadfence();
    __syncthreads();
    if (tid == 0)
      __hip_atomic_store(&flags[fbase + cc], t + 1, __ATOMIC_RELEASE,
                         __HIP_MEMORY_SCOPE_AGENT);
  }
}

// ---------- fp32 flash attention (exact), bf16 in/out ----------
__global__ __launch_bounds__(256) void attn_kernel(
    const unsigned short* __restrict__ h, unsigned short* __restrict__ attnout)
{
  const int qt = blockIdx.x, head = blockIdx.y, b = blockIdx.z;
  const int tid = threadIdx.x;

  __shared__ float q_lds[64 * 68];
  __shared__ float ks_lds[64 * 68];   // k tile, then reused for p values
  __shared__ float v_lds[64 * 68];
  __shared__ float corr_lds[64];
  __shared__ float lsum_lds[64];

  const long qbase = ((long)b * L_) * 512;
  const long kbase = ((long)(B_ + b) * L_) * 512;
  const long vbase = ((long)(2 * B_ + b) * L_) * 512;

#pragma unroll
  for (int p = 0; p < 2; ++p) {
    int idx = p * 256 + tid;
    int row = idx >> 3, c8 = (idx & 7) << 3;
    u16x8 v8 = *(const u16x8*)(h + qbase + (long)(qt * 64 + row) * 512 + head * 64 + c8);
#pragma unroll
    for (int j = 0; j < 8; ++j) q_lds[row * 68 + c8 + j] = bf2f(v8[j]);
  }
  float m_run = -1e30f, lsum = 0.f;
  float acc[16];
#pragma unroll
  for (int j = 0; j < 16; ++j) acc[j] = 0.f;
  const int tq = tid & 15, tk = tid >> 4;
  const int oq = tid >> 2, od = (tid & 3) * 16;

  for (int kt = 0; kt < 8; ++kt) {
    __syncthreads();
#pragma unroll
    for (int p = 0; p < 2; ++p) {
      int idx = p * 256 + tid;
      int row = idx >> 3, c8 = (idx & 7) << 3;
      u16x8 kv = *(const u16x8*)(h + kbase + (long)(kt * 64 + row) * 512 + head * 64 + c8);
      u16x8 vv = *(const u16x8*)(h + vbase + (long)(kt * 64 + row) * 512 + head * 64 + c8);
#pragma unroll
      for (int j = 0; j < 8; ++j) {
        ks_lds[row * 68 + c8 + j] = bf2f(kv[j]);
        v_lds[row * 68 + c8 + j]  = bf2f(vv[j]);
      }
    }
    __syncthreads();
    float sc[16];
#pragma unroll
    for (int x = 0; x < 16; ++x) sc[x] = 0.f;
    for (int d4 = 0; d4 < 64; d4 += 4) {
      f32x4 qv[4], kv4[4];
#pragma unroll
      for (int a = 0; a < 4; ++a) qv[a] = *(const f32x4*)&q_lds[(tq + a * 16) * 68 + d4];
#pragma unroll
      for (int c = 0; c < 4; ++c) kv4[c] = *(const f32x4*)&ks_lds[(tk + c * 16) * 68 + d4];
#pragma unroll
      for (int a = 0; a < 4; ++a)
#pragma unroll
        for (int c = 0; c < 4; ++c)
          sc[a * 4 + c] += qv[a][0] * kv4[c][0] + qv[a][1] * kv4[c][1] +
                           qv[a][2] * kv4[c][2] + qv[a][3] * kv4[c][3];
    }
    __syncthreads();
#pragma unroll
    for (int a = 0; a < 4; ++a)
#pragma unroll
      for (int c = 0; c < 4; ++c)
        ks_lds[(tq + a * 16) * 68 + (tk + c * 16)] = sc[a * 4 + c] * 0.125f;
    __syncthreads();
    if (tid < 64) {
      int q = tid;
      float mx = m_run;
      for (int k = 0; k < 64; ++k) mx = fmaxf(mx, ks_lds[q * 68 + k]);
      float corr = __expf(m_run - mx);
      float rs = 0.f;
      for (int k = 0; k < 64; ++k) {
        float p = __expf(ks_lds[q * 68 + k] - mx);
        ks_lds[q * 68 + k] = p;
        rs += p;
      }
      lsum = lsum * corr + rs;
      m_run = mx;
      corr_lds[q] = corr;
    }
    __syncthreads();
    {
      float cr = corr_lds[oq];
#pragma unroll
      for (int j = 0; j < 16; ++j) acc[j] *= cr;
      for (int k = 0; k < 64; ++k) {
        float p = ks_lds[oq * 68 + k];
        f32x4 v0 = *(const f32x4*)&v_lds[k * 68 + od];
        f32x4 v1 = *(const f32x4*)&v_lds[k * 68 + od + 4];
        f32x4 v2 = *(const f32x4*)&v_lds[k * 68 + od + 8];
        f32x4 v3 = *(const f32x4*)&v_lds[k * 68 + od + 12];
#pragma unroll
        for (int j = 0; j < 4; ++j) {
          acc[j]      += p * v0[j];
          acc[4 + j]  += p * v1[j];
          acc[8 + j]  += p * v2[j];
          acc[12 + j] += p * v3[j];
        }
      }
    }
  }
  if (tid < 64) lsum_lds[tid] = lsum;
  __syncthreads();
  float inv = 1.0f / lsum_lds[oq];
  unsigned short* op = attnout + ((long)(b * L_ + qt * 64 + oq)) * 512 + head * 64 + od;
#pragma unroll
  for (int j = 0; j < 16; ++j) op[j] = f2bf(acc[j] * inv);
}

// ---------- projection GEMM: C[16384,512] = A[16384,512]·B[512,512]^T + bias ----------
__global__ __launch_bounds__(256) void gemm_proj(
    const unsigned short* __restrict__ A, const unsigned short* __restrict__ Bw,
    const float* __restrict__ bias, float* __restrict__ C)
{
  const int m0 = blockIdx.y * 128, n0 = blockIdx.x * 128;
  __shared__ unsigned short sA[128 * 64];
  __shared__ unsigned short sB[128 * 64];
  const int tid = threadIdx.x, lane = tid & 63, wv = tid >> 6;
  const int wr = wv >> 1, wc = wv & 1;
  f32x4 acc[4][4];
#pragma unroll
  for (int i = 0; i < 4; ++i)
#pragma unroll
    for (int j = 0; j < 4; ++j) acc[i][j] = (f32x4){0.f, 0.f, 0.f, 0.f};

  for (int kt = 0; kt < 512; kt += 64) {
#pragma unroll
    for (int p = 0; p < 4; ++p) {
      int g = p * 256 + tid;
      int r = g >> 3, c8 = (g & 7) << 3;
      int bo = ((r << 7) + (c8 << 1)) ^ ((r & 7) << 4);
      *(u16x8*)((char*)sA + bo) = *(const u16x8*)(A + (long)(m0 + r) * 512 + kt + c8);
      *(u16x8*)((char*)sB + bo) = *(const u16x8*)(Bw + (long)(n0 + r) * 512 + kt + c8);
    }
    __syncthreads();
#pragma unroll
    for (int kf = 0; kf < 2; ++kf) {
      int cb = kf * 32 + ((lane >> 4) << 3);
      bf16x8 av[4], bv[4];
#pragma unroll
      for (int i = 0; i < 4; ++i) {
        int ra = wr * 64 + i * 16 + (lane & 15);
        av[i] = *(const bf16x8*)((const char*)sA + (((ra << 7) + (cb << 1)) ^ ((ra & 7) << 4)));
        int rb = wc * 64 + i * 16 + (lane & 15);
        bv[i] = *(const bf16x8*)((const char*)sB + (((rb << 7) + (cb << 1)) ^ ((rb & 7) << 4)));
      }
#pragma unroll
      for (int i = 0; i < 4; ++i)
#pragma unroll
        for (int j = 0; j < 4; ++j)
          acc[i][j] = __builtin_amdgcn_mfma_f32_16x16x32_bf16(av[i], bv[j], acc[i][j], 0, 0, 0);
    }
    __syncthreads();
  }
#pragma unroll
  for (int i = 0; i < 4; ++i) {
    int gm0 = m0 + wr * 64 + i * 16 + ((lane >> 4) << 2);
#pragma unroll
    for (int j = 0; j < 4; ++j) {
      int gn = n0 + wc * 64 + j * 16 + (lane & 15);
      float bv = bias[gn];
#pragma unroll
      for (int r = 0; r < 4; ++r)
        C[(long)(gm0 + r) * 512 + gn] = acc[i][j][r] + bv;
    }
  }
}

// ---------- host ----------
extern "C" void kernel_launch(void* const* d_in, const int* in_sizes, int n_in,
                              void* d_out, int out_size, void* d_ws, size_t ws_size,
                              hipStream_t stream)
{
  const float* xin[3]  = {(const float*)d_in[0], (const float*)d_in[1], (const float*)d_in[2]};
  const float* w_ih[3] = {(const float*)d_in[3], (const float*)d_in[7],  (const float*)d_in[11]};
  const float* w_hh[3] = {(const float*)d_in[4], (const float*)d_in[8],  (const float*)d_in[12]};
  const float* b_ih[3] = {(const float*)d_in[5], (const float*)d_in[9],  (const float*)d_in[13]};
  const float* b_hh[3] = {(const float*)d_in[6], (const float*)d_in[10], (const float*)d_in[14]};
  const float* w_out = (const float*)d_in[15];
  const float* b_out = (const float*)d_in[16];

  // layout (bytes):
  //   xs      @ 0          50,331,648   [96][512][512] bf16
  //   hout    @ 50331648   50,331,648   [96][512][512] bf16
  //   wcat    @ 100663296  12,582,912   [3][2048][1024] bf16
  //   wouts   @ 113246208     524,288   [512][512] bf16
  //   attnout @ 113770496  16,777,216   [16384][512] bf16
  //   flags   @ 130547712       1,024
  const size_t TOTAL = 130548736ULL;
  if (ws_size < TOTAL) {  // sentinel: distinguishes ws-too-small (err~1.09) from launch failure (err 0.0908)
    k_fill<<<dim3(1024), dim3(256), 0, stream>>>((float*)d_out, (long)out_size, 1.0f);
    return;
  }
  char* ws = (char*)d_ws;
  unsigned short* xs      = (unsigned short*)(ws);
  unsigned short* hout    = (unsigned short*)(ws + 50331648);
  unsigned short* wcat    = (unsigned short*)(ws + 100663296);
  unsigned short* wouts   = (unsigned short*)(ws + 113246208);
  unsigned short* attnout = (unsigned short*)(ws + 113770496);
  int*            flags   = (int*)(ws + 130547712);

  for (int l = 0; l < 3; ++l) {
    k_cvt<<<dim3(4096), dim3(256), 0, stream>>>(xin[l], xs + (long)l * 8388608, 8388608L);
    k_pack_w<<<dim3(1024), dim3(256), 0, stream>>>(w_ih[l], w_hh[l], wcat + (long)l * 2097152);
  }
  k_cvt<<<dim3(128), dim3(256), 0, stream>>>(w_out, wouts, 262144L);

  hipMemsetAsync(flags, 0, 1024, stream);
  LBias bb;
  for (int l = 0; l < 3; ++l) { bb.bi[l] = b_ih[l]; bb.bh[l] = b_hh[l]; }
  lstm_rec<<<dim3(128), dim3(512), 0, stream>>>(wcat, xs, bb, hout, flags);

  attn_kernel<<<dim3(8, 8, 32), dim3(256), 0, stream>>>(hout, attnout);

  gemm_proj<<<dim3(4, 128), dim3(256), 0, stream>>>(attnout, wouts, b_out, (float*)d_out);
}

// Round 3
// 2094.211 us; speedup vs baseline: 5.2524x; 5.2524x over previous
//
#include <hip/hip_runtime.h>
#include <cstdint>

#define B_ 32
#define L_ 512
#define G4_ 2048

typedef __bf16          bf16x8 __attribute__((ext_vector_type(8)));
typedef float           f32x4  __attribute__((ext_vector_type(4)));
typedef unsigned short  u16x8  __attribute__((ext_vector_type(8)));

__device__ __forceinline__ unsigned short f2bf(float v) {
  unsigned int u = __float_as_uint(v);
  unsigned int r = u + 0x7fffu + ((u >> 16) & 1u);   // RNE
  return (unsigned short)(r >> 16);
}
__device__ __forceinline__ float bf2f(unsigned short u) {
  return __uint_as_float(((unsigned int)u) << 16);
}
__device__ __forceinline__ float sigf(float x) { return 1.0f / (1.0f + __expf(-x)); }
__device__ __forceinline__ float tanhf_(float x) { return 1.0f - 2.0f / (__expf(2.0f * x) + 1.0f); }

// ---------- sentinel (ws too small): d_out = 1.0 everywhere ----------
__global__ __launch_bounds__(256) void k_fill(float* o, long n, float v) {
  for (long i = (long)blockIdx.x * 256 + threadIdx.x; i < n; i += (long)gridDim.x * 256) o[i] = v;
}

// ---------- fp32 -> bf16 flat convert ----------
__global__ __launch_bounds__(256) void k_cvt(const float* __restrict__ in,
                                             unsigned short* __restrict__ out, long n) {
  long i = ((long)blockIdx.x * 256 + threadIdx.x) * 8;
  if (i >= n) return;
  const float4* p = (const float4*)(in + i);
  float4 a = p[0], b = p[1];
  u16x8 o;
  o[0] = f2bf(a.x); o[1] = f2bf(a.y); o[2] = f2bf(a.z); o[3] = f2bf(a.w);
  o[4] = f2bf(b.x); o[5] = f2bf(b.y); o[6] = f2bf(b.z); o[7] = f2bf(b.w);
  *(u16x8*)(out + i) = o;
}

// ---------- pack [w_ih | w_hh] -> wcat[2048][1024] bf16 ----------
__global__ __launch_bounds__(256) void k_pack_w(const float* __restrict__ wih,
                                                const float* __restrict__ whh,
                                                unsigned short* __restrict__ wcat) {
  long i = ((long)blockIdx.x * 256 + threadIdx.x) * 8;
  int row = (int)(i >> 10), col = (int)(i & 1023);
  const float* src = (col < 512) ? (wih + (long)row * 512 + col)
                                 : (whh + (long)row * 512 + (col - 512));
  const float4* p = (const float4*)src;
  float4 a = p[0], b = p[1];
  u16x8 o;
  o[0] = f2bf(a.x); o[1] = f2bf(a.y); o[2] = f2bf(a.z); o[3] = f2bf(a.w);
  o[4] = f2bf(b.x); o[5] = f2bf(b.y); o[6] = f2bf(b.z); o[7] = f2bf(b.w);
  *(u16x8*)(wcat + i) = o;
}

// ---------- persistent LSTM recurrence, fused Wx+Wh ----------
// 96 blocks = 6 row-groups (layer l, batch-half b0; 16 seqs) x 16 col-chunks (32 units).
// W chunk [128 gate-rows][1024] bf16 in registers (af[32] = 128 VGPR/lane; lb(512,1)).
// Sync protocol (all agent scope, no XCD-placement assumption for correctness):
//   writer: h via RELAXED atomic stores (sc1 write-through) -> __syncthreads (vmcnt drain)
//           -> RELAXED flag store.
//   reader: RELAXED flag poll (no invalidate!) -> ONE acquire fence (buffer_inv) by wave 0
//           -> plain vectorized h loads.
// h global-load latency hidden under x-half MFMAs.
struct LBias { const float* bi[3]; const float* bh[3]; };

__global__ __launch_bounds__(512, 1) void lstm_rec(
    const unsigned short* __restrict__ wcat,  // [3][2048][1024]
    const unsigned short* __restrict__ xs,    // [96][512][512]
    LBias bb,
    unsigned short* __restrict__ hout,        // [96][512][512]
    int* __restrict__ flags)                  // [6][16]
{
  const int r8 = blockIdx.x & 7;
  if (r8 >= 6) return;
  const int rg = r8, cc = blockIdx.x >> 3;
  const int l = rg >> 1, b0 = (rg & 1) * 16;
  const int tid = threadIdx.x, lane = tid & 63, wv = tid >> 6;

  __shared__ unsigned short sXH[16 * 1024];   // [16 seqs][x(512)|h(512)] swizzled
  __shared__ float sD[128 * 17];
  __shared__ float sBias[128];

  if (tid < 128) {
    int grow = (tid >> 5) * 512 + cc * 32 + (tid & 31);
    sBias[tid] = bb.bi[l][grow] + bb.bh[l][grow];
  }

  bf16x8 af[32];                              // 128 VGPR of weights
  {
    int m = wv * 16 + (lane & 15);
    int grow = (m >> 5) * 512 + cc * 32 + (m & 31);
    const unsigned short* Wp = wcat + ((long)l * G4_ + grow) * 1024 + ((lane >> 4) << 3);
#pragma unroll
    for (int kf = 0; kf < 32; ++kf) af[kf] = *(const bf16x8*)(Wp + kf * 32);
  }

  const int sx = tid >> 5;                    // seq 0..15
  const int c16 = (tid & 31) << 4;            // element offset of 16-elem chunk
  const int cxb = c16 << 1;                   // byte offset in 1024B half-row
  const long seqbase = ((long)(l * B_ + b0 + sx)) * L_;
  u16x8 xr0, xr1;
  {
    const unsigned short* p = xs + (seqbase + 0) * 512 + c16;
    xr0 = *(const u16x8*)p;
    xr1 = *(const u16x8*)(p + 8);
  }
  const int fbase = rg * 16;
  const int u = tid & 31, sq = tid >> 5;
  const int rb = sx << 11, sw = (sx & 7) << 4;
  float creg = 0.f;
  __syncthreads();

  for (int t = 0; t < L_; ++t) {
    // stage x(t) (prefetched regs) into x-half of sXH
    *(u16x8*)((char*)sXH + ((rb + cxb) ^ sw))      = xr0;
    *(u16x8*)((char*)sXH + ((rb + cxb + 16) ^ sw)) = xr1;
    // issue x(t+1) prefetch
    if (t + 1 < L_) {
      const unsigned short* p = xs + (seqbase + t + 1) * 512 + c16;
      xr0 = *(const u16x8*)p;
      xr1 = *(const u16x8*)(p + 8);
    }
    // wait for h(t-1) producers: relaxed poll, then one acquire fence (wave 0)
    if (t > 0) {
      if (tid < 16) {
        while (__hip_atomic_load(&flags[fbase + tid], __ATOMIC_RELAXED,
                                 __HIP_MEMORY_SCOPE_AGENT) < t)
          __builtin_amdgcn_s_sleep(1);
      }
      if (wv == 0) __builtin_amdgcn_fence(__ATOMIC_ACQUIRE, "agent");
    }
    __syncthreads();

    // issue h(t-1) plain vectorized loads (latency hidden under x-half MFMA)
    u16x8 hr0, hr1;
    if (t > 0) {
      const unsigned short* p = hout + (seqbase + t - 1) * 512 + c16;
      hr0 = *(const u16x8*)p;
      hr1 = *(const u16x8*)(p + 8);
    } else {
      hr0 = (u16x8){0,0,0,0,0,0,0,0};
      hr1 = (u16x8){0,0,0,0,0,0,0,0};
    }

    f32x4 acc = (f32x4){0.f, 0.f, 0.f, 0.f};
    const int srow = lane & 15;
    const int rbm = srow << 11, swm = (srow & 7) << 4;
    const int kob = (lane >> 4) << 4;
    // x-half: cols [0,512) -> kf 0..15
#pragma unroll
    for (int kf = 0; kf < 16; ++kf) {
      bf16x8 bv = *(const bf16x8*)((const char*)sXH + ((rbm + kf * 64 + kob) ^ swm));
      acc = __builtin_amdgcn_mfma_f32_16x16x32_bf16(af[kf], bv, acc, 0, 0, 0);
    }
    // land h into h-half of sXH
    {
      int o0 = rb + 1024 + cxb;
      *(u16x8*)((char*)sXH + (o0 ^ sw))        = hr0;
      *(u16x8*)((char*)sXH + ((o0 + 16) ^ sw)) = hr1;
    }
    __syncthreads();
    // h-half: cols [512,1024) -> kf 16..31
#pragma unroll
    for (int kf = 16; kf < 32; ++kf) {
      bf16x8 bv = *(const bf16x8*)((const char*)sXH + ((rbm + kf * 64 + kob) ^ swm));
      acc = __builtin_amdgcn_mfma_f32_16x16x32_bf16(af[kf], bv, acc, 0, 0, 0);
    }
    {
      int mb = wv * 16 + ((lane >> 4) << 2);
      int scn = lane & 15;
#pragma unroll
      for (int r = 0; r < 4; ++r) sD[(mb + r) * 17 + scn] = acc[r] + sBias[mb + r];
    }
    __syncthreads();
    // gates: thread owns cell (sq, u)
    {
      float Pi = sD[(u) * 17 + sq];
      float Pf = sD[(32 + u) * 17 + sq];
      float Pg = sD[(64 + u) * 17 + sq];
      float Po = sD[(96 + u) * 17 + sq];
      float iv = sigf(Pi), fv = sigf(Pf), gv = tanhf_(Pg), ov = sigf(Po);
      creg = fv * creg + iv * gv;
      float h = ov * tanhf_(creg);
      unsigned int hb16 = (unsigned int)f2bf(h);
      unsigned int other = (unsigned int)__shfl_xor((int)hb16, 1);
      if ((tid & 1) == 0) {
        unsigned int pk = hb16 | (other << 16);
        unsigned int* dst =
            (unsigned int*)(hout + (((long)(l * B_ + b0 + sq)) * L_ + t) * 512 + cc * 32 + u);
        __hip_atomic_store(dst, pk, __ATOMIC_RELAXED, __HIP_MEMORY_SCOPE_AGENT);
      }
    }
    __syncthreads();  // drains vmcnt(0): h stores complete (sc1 -> coherence point)
    if (tid == 0)
      __hip_atomic_store(&flags[fbase + cc], t + 1, __ATOMIC_RELAXED,
                         __HIP_MEMORY_SCOPE_AGENT);
  }
}

// ---------- fp32 flash attention (exact), bf16 in/out ----------
__global__ __launch_bounds__(256) void attn_kernel(
    const unsigned short* __restrict__ h, unsigned short* __restrict__ attnout)
{
  const int qt = blockIdx.x, head = blockIdx.y, b = blockIdx.z;
  const int tid = threadIdx.x;

  __shared__ float q_lds[64 * 68];
  __shared__ float ks_lds[64 * 68];
  __shared__ float v_lds[64 * 68];
  __shared__ float corr_lds[64];
  __shared__ float lsum_lds[64];

  const long qbase = ((long)b * L_) * 512;
  const long kbase = ((long)(B_ + b) * L_) * 512;
  const long vbase = ((long)(2 * B_ + b) * L_) * 512;

#pragma unroll
  for (int p = 0; p < 2; ++p) {
    int idx = p * 256 + tid;
    int row = idx >> 3, c8 = (idx & 7) << 3;
    u16x8 v8 = *(const u16x8*)(h + qbase + (long)(qt * 64 + row) * 512 + head * 64 + c8);
#pragma unroll
    for (int j = 0; j < 8; ++j) q_lds[row * 68 + c8 + j] = bf2f(v8[j]);
  }
  float m_run = -1e30f, lsum = 0.f;
  float acc[16];
#pragma unroll
  for (int j = 0; j < 16; ++j) acc[j] = 0.f;
  const int tq = tid & 15, tk = tid >> 4;
  const int oq = tid >> 2, od = (tid & 3) * 16;

  for (int kt = 0; kt < 8; ++kt) {
    __syncthreads();
#pragma unroll
    for (int p = 0; p < 2; ++p) {
      int idx = p * 256 + tid;
      int row = idx >> 3, c8 = (idx & 7) << 3;
      u16x8 kv = *(const u16x8*)(h + kbase + (long)(kt * 64 + row) * 512 + head * 64 + c8);
      u16x8 vv = *(const u16x8*)(h + vbase + (long)(kt * 64 + row) * 512 + head * 64 + c8);
#pragma unroll
      for (int j = 0; j < 8; ++j) {
        ks_lds[row * 68 + c8 + j] = bf2f(kv[j]);
        v_lds[row * 68 + c8 + j]  = bf2f(vv[j]);
      }
    }
    __syncthreads();
    float sc[16];
#pragma unroll
    for (int x = 0; x < 16; ++x) sc[x] = 0.f;
    for (int d4 = 0; d4 < 64; d4 += 4) {
      f32x4 qv[4], kv4[4];
#pragma unroll
      for (int a = 0; a < 4; ++a) qv[a] = *(const f32x4*)&q_lds[(tq + a * 16) * 68 + d4];
#pragma unroll
      for (int c = 0; c < 4; ++c) kv4[c] = *(const f32x4*)&ks_lds[(tk + c * 16) * 68 + d4];
#pragma unroll
      for (int a = 0; a < 4; ++a)
#pragma unroll
        for (int c = 0; c < 4; ++c)
          sc[a * 4 + c] += qv[a][0] * kv4[c][0] + qv[a][1] * kv4[c][1] +
                           qv[a][2] * kv4[c][2] + qv[a][3] * kv4[c][3];
    }
    __syncthreads();
#pragma unroll
    for (int a = 0; a < 4; ++a)
#pragma unroll
      for (int c = 0; c < 4; ++c)
        ks_lds[(tq + a * 16) * 68 + (tk + c * 16)] = sc[a * 4 + c] * 0.125f;
    __syncthreads();
    if (tid < 64) {
      int q = tid;
      float mx = m_run;
      for (int k = 0; k < 64; ++k) mx = fmaxf(mx, ks_lds[q * 68 + k]);
      float corr = __expf(m_run - mx);
      float rs = 0.f;
      for (int k = 0; k < 64; ++k) {
        float p = __expf(ks_lds[q * 68 + k] - mx);
        ks_lds[q * 68 + k] = p;
        rs += p;
      }
      lsum = lsum * corr + rs;
      m_run = mx;
      corr_lds[q] = corr;
    }
    __syncthreads();
    {
      float cr = corr_lds[oq];
#pragma unroll
      for (int j = 0; j < 16; ++j) acc[j] *= cr;
      for (int k = 0; k < 64; ++k) {
        float p = ks_lds[oq * 68 + k];
        f32x4 v0 = *(const f32x4*)&v_lds[k * 68 + od];
        f32x4 v1 = *(const f32x4*)&v_lds[k * 68 + od + 4];
        f32x4 v2 = *(const f32x4*)&v_lds[k * 68 + od + 8];
        f32x4 v3 = *(const f32x4*)&v_lds[k * 68 + od + 12];
#pragma unroll
        for (int j = 0; j < 4; ++j) {
          acc[j]      += p * v0[j];
          acc[4 + j]  += p * v1[j];
          acc[8 + j]  += p * v2[j];
          acc[12 + j] += p * v3[j];
        }
      }
    }
  }
  if (tid < 64) lsum_lds[tid] = lsum;
  __syncthreads();
  float inv = 1.0f / lsum_lds[oq];
  unsigned short* op = attnout + ((long)(b * L_ + qt * 64 + oq)) * 512 + head * 64 + od;
#pragma unroll
  for (int j = 0; j < 16; ++j) op[j] = f2bf(acc[j] * inv);
}

// ---------- projection GEMM: C[16384,512] = A[16384,512]·B[512,512]^T + bias ----------
__global__ __launch_bounds__(256) void gemm_proj(
    const unsigned short* __restrict__ A, const unsigned short* __restrict__ Bw,
    const float* __restrict__ bias, float* __restrict__ C)
{
  const int m0 = blockIdx.y * 128, n0 = blockIdx.x * 128;
  __shared__ unsigned short sA[128 * 64];
  __shared__ unsigned short sB[128 * 64];
  const int tid = threadIdx.x, lane = tid & 63, wv = tid >> 6;
  const int wr = wv >> 1, wc = wv & 1;
  f32x4 acc[4][4];
#pragma unroll
  for (int i = 0; i < 4; ++i)
#pragma unroll
    for (int j = 0; j < 4; ++j) acc[i][j] = (f32x4){0.f, 0.f, 0.f, 0.f};

  for (int kt = 0; kt < 512; kt += 64) {
#pragma unroll
    for (int p = 0; p < 4; ++p) {
      int g = p * 256 + tid;
      int r = g >> 3, c8 = (g & 7) << 3;
      int bo = ((r << 7) + (c8 << 1)) ^ ((r & 7) << 4);
      *(u16x8*)((char*)sA + bo) = *(const u16x8*)(A + (long)(m0 + r) * 512 + kt + c8);
      *(u16x8*)((char*)sB + bo) = *(const u16x8*)(Bw + (long)(n0 + r) * 512 + kt + c8);
    }
    __syncthreads();
#pragma unroll
    for (int kf = 0; kf < 2; ++kf) {
      int cb = kf * 32 + ((lane >> 4) << 3);
      bf16x8 av[4], bv[4];
#pragma unroll
      for (int i = 0; i < 4; ++i) {
        int ra = wr * 64 + i * 16 + (lane & 15);
        av[i] = *(const bf16x8*)((const char*)sA + (((ra << 7) + (cb << 1)) ^ ((ra & 7) << 4)));
        int rb = wc * 64 + i * 16 + (lane & 15);
        bv[i] = *(const bf16x8*)((const char*)sB + (((rb << 7) + (cb << 1)) ^ ((rb & 7) << 4)));
      }
#pragma unroll
      for (int i = 0; i < 4; ++i)
#pragma unroll
        for (int j = 0; j < 4; ++j)
          acc[i][j] = __builtin_amdgcn_mfma_f32_16x16x32_bf16(av[i], bv[j], acc[i][j], 0, 0, 0);
    }
    __syncthreads();
  }
#pragma unroll
  for (int i = 0; i < 4; ++i) {
    int gm0 = m0 + wr * 64 + i * 16 + ((lane >> 4) << 2);
#pragma unroll
    for (int j = 0; j < 4; ++j) {
      int gn = n0 + wc * 64 + j * 16 + (lane & 15);
      float bv = bias[gn];
#pragma unroll
      for (int r = 0; r < 4; ++r)
        C[(long)(gm0 + r) * 512 + gn] = acc[i][j][r] + bv;
    }
  }
}

// ---------- host ----------
extern "C" void kernel_launch(void* const* d_in, const int* in_sizes, int n_in,
                              void* d_out, int out_size, void* d_ws, size_t ws_size,
                              hipStream_t stream)
{
  const float* xin[3]  = {(const float*)d_in[0], (const float*)d_in[1], (const float*)d_in[2]};
  const float* w_ih[3] = {(const float*)d_in[3], (const float*)d_in[7],  (const float*)d_in[11]};
  const float* w_hh[3] = {(const float*)d_in[4], (const float*)d_in[8],  (const float*)d_in[12]};
  const float* b_ih[3] = {(const float*)d_in[5], (const float*)d_in[9],  (const float*)d_in[13]};
  const float* b_hh[3] = {(const float*)d_in[6], (const float*)d_in[10], (const float*)d_in[14]};
  const float* w_out = (const float*)d_in[15];
  const float* b_out = (const float*)d_in[16];

  const size_t TOTAL = 130548736ULL;
  if (ws_size < TOTAL) {
    k_fill<<<dim3(1024), dim3(256), 0, stream>>>((float*)d_out, (long)out_size, 1.0f);
    return;
  }
  char* ws = (char*)d_ws;
  unsigned short* xs      = (unsigned short*)(ws);
  unsigned short* hout    = (unsigned short*)(ws + 50331648);
  unsigned short* wcat    = (unsigned short*)(ws + 100663296);
  unsigned short* wouts   = (unsigned short*)(ws + 113246208);
  unsigned short* attnout = (unsigned short*)(ws + 113770496);
  int*            flags   = (int*)(ws + 130547712);

  for (int l = 0; l < 3; ++l) {
    k_cvt<<<dim3(4096), dim3(256), 0, stream>>>(xin[l], xs + (long)l * 8388608, 8388608L);
    k_pack_w<<<dim3(1024), dim3(256), 0, stream>>>(w_ih[l], w_hh[l], wcat + (long)l * 2097152);
  }
  k_cvt<<<dim3(128), dim3(256), 0, stream>>>(w_out, wouts, 262144L);

  hipMemsetAsync(flags, 0, 1024, stream);
  LBias bb;
  for (int l = 0; l < 3; ++l) { bb.bi[l] = b_ih[l]; bb.bh[l] = b_hh[l]; }
  lstm_rec<<<dim3(128), dim3(512), 0, stream>>>(wcat, xs, bb, hout, flags);

  attn_kernel<<<dim3(8, 8, 32), dim3(256), 0, stream>>>(hout, attnout);

  gemm_proj<<<dim3(4, 128), dim3(256), 0, stream>>>(attnout, wouts, b_out, (float*)d_out);
}

// Round 4
// 1487.349 us; speedup vs baseline: 7.3955x; 1.4080x over previous
//
#include <hip/hip_runtime.h>
#include <cstdint>

#define B_ 32
#define L_ 512
#define G4_ 2048

typedef __bf16          bf16x8 __attribute__((ext_vector_type(8)));
typedef float           f32x4  __attribute__((ext_vector_type(4)));
typedef unsigned short  u16x8  __attribute__((ext_vector_type(8)));
typedef unsigned int    u32x4  __attribute__((ext_vector_type(4)));

__device__ __forceinline__ unsigned short f2bf(float v) {
  unsigned int u = __float_as_uint(v);
  unsigned int r = u + 0x7fffu + ((u >> 16) & 1u);   // RNE
  return (unsigned short)(r >> 16);
}
__device__ __forceinline__ float bf2f(unsigned short u) {
  return __uint_as_float(((unsigned int)u) << 16);
}
__device__ __forceinline__ float sigf(float x) { return 1.0f / (1.0f + __expf(-x)); }
__device__ __forceinline__ float tanhf_(float x) { return 1.0f - 2.0f / (__expf(2.0f * x) + 1.0f); }

// ---------- sentinel (ws too small): d_out = 1.0 everywhere ----------
__global__ __launch_bounds__(256) void k_fill(float* o, long n, float v) {
  for (long i = (long)blockIdx.x * 256 + threadIdx.x; i < n; i += (long)gridDim.x * 256) o[i] = v;
}

// ---------- fp32 -> bf16 flat convert ----------
__global__ __launch_bounds__(256) void k_cvt(const float* __restrict__ in,
                                             unsigned short* __restrict__ out, long n) {
  long i = ((long)blockIdx.x * 256 + threadIdx.x) * 8;
  if (i >= n) return;
  const float4* p = (const float4*)(in + i);
  float4 a = p[0], b = p[1];
  u16x8 o;
  o[0] = f2bf(a.x); o[1] = f2bf(a.y); o[2] = f2bf(a.z); o[3] = f2bf(a.w);
  o[4] = f2bf(b.x); o[5] = f2bf(b.y); o[6] = f2bf(b.z); o[7] = f2bf(b.w);
  *(u16x8*)(out + i) = o;
}

// ---------- pack [w_ih | w_hh] -> wcat[2048][1024] bf16, gate-permuted ----------
// New row nr = cc*128 + wv*16 + OR, where OR&3 = gate, OR>>2 = unit_local(0..3):
// orig grow = (OR&3)*512 + cc*32 + wv*4 + (OR>>2).
// This makes each lane's MFMA acc[r] = gate r of ONE unit -> lane-local gate math.
__global__ __launch_bounds__(256) void k_pack_w(const float* __restrict__ wih,
                                                const float* __restrict__ whh,
                                                unsigned short* __restrict__ wcat) {
  long i = ((long)blockIdx.x * 256 + threadIdx.x) * 8;
  int nr = (int)(i >> 10), col = (int)(i & 1023);
  int cc = nr >> 7, wvp = (nr >> 4) & 7, OR = nr & 15;
  int grow = (OR & 3) * 512 + cc * 32 + wvp * 4 + (OR >> 2);
  const float* src = (col < 512) ? (wih + (long)grow * 512 + col)
                                 : (whh + (long)grow * 512 + (col - 512));
  const float4* p = (const float4*)src;
  float4 a = p[0], b = p[1];
  u16x8 o;
  o[0] = f2bf(a.x); o[1] = f2bf(a.y); o[2] = f2bf(a.z); o[3] = f2bf(a.w);
  o[4] = f2bf(b.x); o[5] = f2bf(b.y); o[6] = f2bf(b.z); o[7] = f2bf(b.w);
  *(u16x8*)(wcat + i) = o;
}

// ---------- persistent LSTM recurrence, fused Wx+Wh ----------
// 96 blocks = 6 row-groups (layer l, batch-half; 16 seqs) x 16 col-chunks (32 units).
// Weights in registers (af[32] = 128 VGPR). Coherence: ALL cross-block traffic
// (flag poll, h loads, h/flag stores) is sc1 (IF-direct) -> NO fences, NO L2
// invalidation. h addresses are write-once/read-after-flag; producer's sc1 h
// stores are vmcnt-drained by __syncthreads before the sc1 flag release.
struct LBias { const float* bi[3]; const float* bh[3]; };

__global__ __launch_bounds__(512, 1) void lstm_rec(
    const unsigned short* __restrict__ wcat,  // [3][2048][1024] gate-permuted
    const unsigned short* __restrict__ xs,    // [96][512][512]
    LBias bb,
    unsigned short* __restrict__ hout,        // [96][512][512]
    int* __restrict__ flags)                  // [96] padded x16 ints
{
  const int r8 = blockIdx.x & 7;
  if (r8 >= 6) return;
  const int rg = r8, cc = blockIdx.x >> 3;
  const int l = rg >> 1, b0 = (rg & 1) * 16;
  const int tid = threadIdx.x, lane = tid & 63, wv = tid >> 6;

  __shared__ unsigned short sXH[16 * 1024];   // [16 seqs][x(512)|h(512)], XOR(row<<4)

  // weights: rows nr = cc*128 + wv*16 + (lane&15)
  bf16x8 af[32];
  {
    int nr = cc * 128 + wv * 16 + (lane & 15);
    const unsigned short* Wp = wcat + ((long)l * G4_ + nr) * 1024 + ((lane >> 4) << 3);
#pragma unroll
    for (int kf = 0; kf < 32; ++kf) af[kf] = *(const bf16x8*)(Wp + kf * 32);
  }
  // per-lane gate biases for unit u
  const int u = cc * 32 + wv * 4 + (lane >> 4);
  float bias[4];
#pragma unroll
  for (int r = 0; r < 4; ++r) bias[r] = bb.bi[l][r * 512 + u] + bb.bh[l][r * 512 + u];

  // staging geometry
  const int sx = tid >> 5;                    // seq row 0..15
  const int slot = tid & 31;                  // 16B slot
  const int sw = sx << 4;
  const int xoff0 = sx * 2048 + slot * 16, xoff1 = xoff0 + 512;
  const int hoff0 = xoff0 + 1024,           hoff1 = hoff0 + 512;
  const int slot8 = slot * 8;                 // element offset
  const long seqbase = ((long)(l * B_ + b0 + sx)) * L_;

  // MFMA read geometry
  const int srow = lane & 15;
  const int rbm = srow << 11, swm = srow << 4;
  const int kob = (lane >> 4) << 4;

  // h-store geometry (lane-local gates): seq = lane&15, unit pair store
  const int hseq = lane & 15;
  const long hrowb = ((long)(l * B_ + b0 + hseq)) * L_;
  const int upair = cc * 16 + wv * 2 + (lane >> 5);

  u16x8 xr0, xr1;
  {
    const unsigned short* p = xs + seqbase * 512 + slot8;
    xr0 = *(const u16x8*)p;
    xr1 = *(const u16x8*)(p + 256);
  }
  const int fbase = rg * 16;
  float creg = 0.f;

  for (int t = 0; t < L_; ++t) {
    // stage x(t) into x-half
    *(u16x8*)((char*)sXH + (xoff0 ^ sw)) = xr0;
    *(u16x8*)((char*)sXH + (xoff1 ^ sw)) = xr1;
    // prefetch x(t+1)
    if (t + 1 < L_) {
      const unsigned short* p = xs + (seqbase + t + 1) * 512 + slot8;
      xr0 = *(const u16x8*)p;
      xr1 = *(const u16x8*)(p + 256);
    }
    // poll producers' flags (sc1 loads; no fence, no invalidation)
    if (t > 0 && wv == 0 && lane < 16) {
      const int* fp = flags + ((fbase + lane) << 4);
      while (__hip_atomic_load(fp, __ATOMIC_RELAXED, __HIP_MEMORY_SCOPE_AGENT) < t) {}
    }
    __syncthreads();

    // issue h(t-1) IF-direct loads; latency hidden under x-half MFMAs
    u32x4 h0 = (u32x4){0, 0, 0, 0}, h1 = (u32x4){0, 0, 0, 0};
    if (t > 0) {
      const unsigned short* hp0 = hout + (seqbase + t - 1) * 512 + slot8;
      const unsigned short* hp1 = hp0 + 256;
      asm volatile("global_load_dwordx4 %0, %1, off sc1"
                   : "=&v"(h0) : "v"(hp0) : "memory");
      asm volatile("global_load_dwordx4 %0, %1, off sc1"
                   : "=&v"(h1) : "v"(hp1) : "memory");
    }

    // x-half MFMAs (kf 0..15), two accumulator chains
    f32x4 aA = (f32x4){0.f, 0.f, 0.f, 0.f};
    f32x4 aB = (f32x4){0.f, 0.f, 0.f, 0.f};
#pragma unroll
    for (int kf = 0; kf < 16; kf += 2) {
      bf16x8 bv0 = *(const bf16x8*)((const char*)sXH + ((rbm + kf * 64 + kob) ^ swm));
      bf16x8 bv1 = *(const bf16x8*)((const char*)sXH + ((rbm + (kf + 1) * 64 + kob) ^ swm));
      aA = __builtin_amdgcn_mfma_f32_16x16x32_bf16(af[kf], bv0, aA, 0, 0, 0);
      aB = __builtin_amdgcn_mfma_f32_16x16x32_bf16(af[kf + 1], bv1, aB, 0, 0, 0);
    }

    // wait h arrivals (manual: asm loads aren't compiler-tracked), then land
    asm volatile("s_waitcnt vmcnt(0)" ::: "memory");
    __builtin_amdgcn_sched_barrier(0);
    *(u16x8*)((char*)sXH + (hoff0 ^ sw)) = *(u16x8*)&h0;
    *(u16x8*)((char*)sXH + (hoff1 ^ sw)) = *(u16x8*)&h1;
    __syncthreads();

    // h-half MFMAs (kf 16..31)
#pragma unroll
    for (int kf = 16; kf < 32; kf += 2) {
      bf16x8 bv0 = *(const bf16x8*)((const char*)sXH + ((rbm + kf * 64 + kob) ^ swm));
      bf16x8 bv1 = *(const bf16x8*)((const char*)sXH + ((rbm + (kf + 1) * 64 + kob) ^ swm));
      aA = __builtin_amdgcn_mfma_f32_16x16x32_bf16(af[kf], bv0, aA, 0, 0, 0);
      aB = __builtin_amdgcn_mfma_f32_16x16x32_bf16(af[kf + 1], bv1, aB, 0, 0, 0);
    }

    // lane-local gates: acc[r] = gate r preact for (unit u, seq hseq)
    {
      float Pi = aA[0] + aB[0] + bias[0];
      float Pf = aA[1] + aB[1] + bias[1];
      float Pg = aA[2] + aB[2] + bias[2];
      float Po = aA[3] + aB[3] + bias[3];
      float iv = sigf(Pi), fv = sigf(Pf), gv = tanhf_(Pg), ov = sigf(Po);
      creg = fv * creg + iv * gv;
      float h = ov * tanhf_(creg);
      unsigned int hb16 = (unsigned int)f2bf(h);
      unsigned int other = (unsigned int)__shfl_xor((int)hb16, 16);
      if ((lane & 16) == 0) {
        unsigned int pk = hb16 | (other << 16);
        unsigned int* dst = (unsigned int*)(hout + (hrowb + t) * 512) + upair;
        __hip_atomic_store(dst, pk, __ATOMIC_RELAXED, __HIP_MEMORY_SCOPE_AGENT);
      }
    }
    __syncthreads();  // drains vmcnt(0) per wave: all h stores at IF
    if (tid == 0)
      __hip_atomic_store(flags + ((fbase + cc) << 4), t + 1, __ATOMIC_RELAXED,
                         __HIP_MEMORY_SCOPE_AGENT);
  }
}

// ---------- fp32 flash attention (exact), bf16 in/out ----------
__global__ __launch_bounds__(256) void attn_kernel(
    const unsigned short* __restrict__ h, unsigned short* __restrict__ attnout)
{
  const int qt = blockIdx.x, head = blockIdx.y, b = blockIdx.z;
  const int tid = threadIdx.x;

  __shared__ float q_lds[64 * 68];
  __shared__ float ks_lds[64 * 68];
  __shared__ float v_lds[64 * 68];
  __shared__ float corr_lds[64];
  __shared__ float lsum_lds[64];

  const long qbase = ((long)b * L_) * 512;
  const long kbase = ((long)(B_ + b) * L_) * 512;
  const long vbase = ((long)(2 * B_ + b) * L_) * 512;

#pragma unroll
  for (int p = 0; p < 2; ++p) {
    int idx = p * 256 + tid;
    int row = idx >> 3, c8 = (idx & 7) << 3;
    u16x8 v8 = *(const u16x8*)(h + qbase + (long)(qt * 64 + row) * 512 + head * 64 + c8);
#pragma unroll
    for (int j = 0; j < 8; ++j) q_lds[row * 68 + c8 + j] = bf2f(v8[j]);
  }
  float m_run = -1e30f, lsum = 0.f;
  float acc[16];
#pragma unroll
  for (int j = 0; j < 16; ++j) acc[j] = 0.f;
  const int tq = tid & 15, tk = tid >> 4;
  const int oq = tid >> 2, od = (tid & 3) * 16;

  for (int kt = 0; kt < 8; ++kt) {
    __syncthreads();
#pragma unroll
    for (int p = 0; p < 2; ++p) {
      int idx = p * 256 + tid;
      int row = idx >> 3, c8 = (idx & 7) << 3;
      u16x8 kv = *(const u16x8*)(h + kbase + (long)(kt * 64 + row) * 512 + head * 64 + c8);
      u16x8 vv = *(const u16x8*)(h + vbase + (long)(kt * 64 + row) * 512 + head * 64 + c8);
#pragma unroll
      for (int j = 0; j < 8; ++j) {
        ks_lds[row * 68 + c8 + j] = bf2f(kv[j]);
        v_lds[row * 68 + c8 + j]  = bf2f(vv[j]);
      }
    }
    __syncthreads();
    float sc[16];
#pragma unroll
    for (int x = 0; x < 16; ++x) sc[x] = 0.f;
    for (int d4 = 0; d4 < 64; d4 += 4) {
      f32x4 qv[4], kv4[4];
#pragma unroll
      for (int a = 0; a < 4; ++a) qv[a] = *(const f32x4*)&q_lds[(tq + a * 16) * 68 + d4];
#pragma unroll
      for (int c = 0; c < 4; ++c) kv4[c] = *(const f32x4*)&ks_lds[(tk + c * 16) * 68 + d4];
#pragma unroll
      for (int a = 0; a < 4; ++a)
#pragma unroll
        for (int c = 0; c < 4; ++c)
          sc[a * 4 + c] += qv[a][0] * kv4[c][0] + qv[a][1] * kv4[c][1] +
                           qv[a][2] * kv4[c][2] + qv[a][3] * kv4[c][3];
    }
    __syncthreads();
#pragma unroll
    for (int a = 0; a < 4; ++a)
#pragma unroll
      for (int c = 0; c < 4; ++c)
        ks_lds[(tq + a * 16) * 68 + (tk + c * 16)] = sc[a * 4 + c] * 0.125f;
    __syncthreads();
    if (tid < 64) {
      int q = tid;
      float mx = m_run;
      for (int k = 0; k < 64; ++k) mx = fmaxf(mx, ks_lds[q * 68 + k]);
      float corr = __expf(m_run - mx);
      float rs = 0.f;
      for (int k = 0; k < 64; ++k) {
        float p = __expf(ks_lds[q * 68 + k] - mx);
        ks_lds[q * 68 + k] = p;
        rs += p;
      }
      lsum = lsum * corr + rs;
      m_run = mx;
      corr_lds[q] = corr;
    }
    __syncthreads();
    {
      float cr = corr_lds[oq];
#pragma unroll
      for (int j = 0; j < 16; ++j) acc[j] *= cr;
      for (int k = 0; k < 64; ++k) {
        float p = ks_lds[oq * 68 + k];
        f32x4 v0 = *(const f32x4*)&v_lds[k * 68 + od];
        f32x4 v1 = *(const f32x4*)&v_lds[k * 68 + od + 4];
        f32x4 v2 = *(const f32x4*)&v_lds[k * 68 + od + 8];
        f32x4 v3 = *(const f32x4*)&v_lds[k * 68 + od + 12];
#pragma unroll
        for (int j = 0; j < 4; ++j) {
          acc[j]      += p * v0[j];
          acc[4 + j]  += p * v1[j];
          acc[8 + j]  += p * v2[j];
          acc[12 + j] += p * v3[j];
        }
      }
    }
  }
  if (tid < 64) lsum_lds[tid] = lsum;
  __syncthreads();
  float inv = 1.0f / lsum_lds[oq];
  unsigned short* op = attnout + ((long)(b * L_ + qt * 64 + oq)) * 512 + head * 64 + od;
#pragma unroll
  for (int j = 0; j < 16; ++j) op[j] = f2bf(acc[j] * inv);
}

// ---------- projection GEMM: C[16384,512] = A[16384,512]·B[512,512]^T + bias ----------
__global__ __launch_bounds__(256) void gemm_proj(
    const unsigned short* __restrict__ A, const unsigned short* __restrict__ Bw,
    const float* __restrict__ bias, float* __restrict__ C)
{
  const int m0 = blockIdx.y * 128, n0 = blockIdx.x * 128;
  __shared__ unsigned short sA[128 * 64];
  __shared__ unsigned short sB[128 * 64];
  const int tid = threadIdx.x, lane = tid & 63, wv = tid >> 6;
  const int wr = wv >> 1, wc = wv & 1;
  f32x4 acc[4][4];
#pragma unroll
  for (int i = 0; i < 4; ++i)
#pragma unroll
    for (int j = 0; j < 4; ++j) acc[i][j] = (f32x4){0.f, 0.f, 0.f, 0.f};

  for (int kt = 0; kt < 512; kt += 64) {
#pragma unroll
    for (int p = 0; p < 4; ++p) {
      int g = p * 256 + tid;
      int r = g >> 3, c8 = (g & 7) << 3;
      int bo = ((r << 7) + (c8 << 1)) ^ ((r & 7) << 4);
      *(u16x8*)((char*)sA + bo) = *(const u16x8*)(A + (long)(m0 + r) * 512 + kt + c8);
      *(u16x8*)((char*)sB + bo) = *(const u16x8*)(Bw + (long)(n0 + r) * 512 + kt + c8);
    }
    __syncthreads();
#pragma unroll
    for (int kf = 0; kf < 2; ++kf) {
      int cb = kf * 32 + ((lane >> 4) << 3);
      bf16x8 av[4], bv[4];
#pragma unroll
      for (int i = 0; i < 4; ++i) {
        int ra = wr * 64 + i * 16 + (lane & 15);
        av[i] = *(const bf16x8*)((const char*)sA + (((ra << 7) + (cb << 1)) ^ ((ra & 7) << 4)));
        int rb = wc * 64 + i * 16 + (lane & 15);
        bv[i] = *(const bf16x8*)((const char*)sB + (((rb << 7) + (cb << 1)) ^ ((rb & 7) << 4)));
      }
#pragma unroll
      for (int i = 0; i < 4; ++i)
#pragma unroll
        for (int j = 0; j < 4; ++j)
          acc[i][j] = __builtin_amdgcn_mfma_f32_16x16x32_bf16(av[i], bv[j], acc[i][j], 0, 0, 0);
    }
    __syncthreads();
  }
#pragma unroll
  for (int i = 0; i < 4; ++i) {
    int gm0 = m0 + wr * 64 + i * 16 + ((lane >> 4) << 2);
#pragma unroll
    for (int j = 0; j < 4; ++j) {
      int gn = n0 + wc * 64 + j * 16 + (lane & 15);
      float bv = bias[gn];
#pragma unroll
      for (int r = 0; r < 4; ++r)
        C[(long)(gm0 + r) * 512 + gn] = acc[i][j][r] + bv;
    }
  }
}

// ---------- host ----------
extern "C" void kernel_launch(void* const* d_in, const int* in_sizes, int n_in,
                              void* d_out, int out_size, void* d_ws, size_t ws_size,
                              hipStream_t stream)
{
  const float* xin[3]  = {(const float*)d_in[0], (const float*)d_in[1], (const float*)d_in[2]};
  const float* w_ih[3] = {(const float*)d_in[3], (const float*)d_in[7],  (const float*)d_in[11]};
  const float* w_hh[3] = {(const float*)d_in[4], (const float*)d_in[8],  (const float*)d_in[12]};
  const float* b_ih[3] = {(const float*)d_in[5], (const float*)d_in[9],  (const float*)d_in[13]};
  const float* b_hh[3] = {(const float*)d_in[6], (const float*)d_in[10], (const float*)d_in[14]};
  const float* w_out = (const float*)d_in[15];
  const float* b_out = (const float*)d_in[16];

  const size_t TOTAL = 130553856ULL;
  if (ws_size < TOTAL) {
    k_fill<<<dim3(1024), dim3(256), 0, stream>>>((float*)d_out, (long)out_size, 1.0f);
    return;
  }
  char* ws = (char*)d_ws;
  unsigned short* xs      = (unsigned short*)(ws);
  unsigned short* hout    = (unsigned short*)(ws + 50331648);
  unsigned short* wcat    = (unsigned short*)(ws + 100663296);
  unsigned short* wouts   = (unsigned short*)(ws + 113246208);
  unsigned short* attnout = (unsigned short*)(ws + 113770496);
  int*            flags   = (int*)(ws + 130547712);   // 96 flags x 64B

  for (int l = 0; l < 3; ++l) {
    k_cvt<<<dim3(4096), dim3(256), 0, stream>>>(xin[l], xs + (long)l * 8388608, 8388608L);
    k_pack_w<<<dim3(1024), dim3(256), 0, stream>>>(w_ih[l], w_hh[l], wcat + (long)l * 2097152);
  }
  k_cvt<<<dim3(128), dim3(256), 0, stream>>>(w_out, wouts, 262144L);

  hipMemsetAsync(flags, 0, 6144, stream);
  LBias bb;
  for (int l = 0; l < 3; ++l) { bb.bi[l] = b_ih[l]; bb.bh[l] = b_hh[l]; }
  lstm_rec<<<dim3(128), dim3(512), 0, stream>>>(wcat, xs, bb, hout, flags);

  attn_kernel<<<dim3(8, 8, 32), dim3(256), 0, stream>>>(hout, attnout);

  gemm_proj<<<dim3(4, 128), dim3(256), 0, stream>>>(attnout, wouts, b_out, (float*)d_out);
}

// Round 5
// 1374.921 us; speedup vs baseline: 8.0002x; 1.0818x over previous
//
#include <hip/hip_runtime.h>
#include <cstdint>

#define B_ 32
#define L_ 512
#define G4_ 2048
#define POI 0xFFFFFFFFu

typedef __bf16          bf16x8 __attribute__((ext_vector_type(8)));
typedef float           f32x4  __attribute__((ext_vector_type(4)));
typedef unsigned short  u16x8  __attribute__((ext_vector_type(8)));
typedef unsigned int    u32x4  __attribute__((ext_vector_type(4)));

__device__ __forceinline__ unsigned short f2bf(float v) {
  unsigned int u = __float_as_uint(v);
  unsigned int r = u + 0x7fffu + ((u >> 16) & 1u);   // RNE
  return (unsigned short)(r >> 16);
}
__device__ __forceinline__ float bf2f(unsigned short u) {
  return __uint_as_float(((unsigned int)u) << 16);
}
__device__ __forceinline__ float sigf(float x) { return 1.0f / (1.0f + __expf(-x)); }
__device__ __forceinline__ float tanhf_(float x) { return 1.0f - 2.0f / (__expf(2.0f * x) + 1.0f); }

// ---------- sentinel (ws too small): d_out = 1.0 everywhere ----------
__global__ __launch_bounds__(256) void k_fill(float* o, long n, float v) {
  for (long i = (long)blockIdx.x * 256 + threadIdx.x; i < n; i += (long)gridDim.x * 256) o[i] = v;
}

// ---------- fp32 -> bf16 flat convert ----------
__global__ __launch_bounds__(256) void k_cvt(const float* __restrict__ in,
                                             unsigned short* __restrict__ out, long n) {
  long i = ((long)blockIdx.x * 256 + threadIdx.x) * 8;
  if (i >= n) return;
  const float4* p = (const float4*)(in + i);
  float4 a = p[0], b = p[1];
  u16x8 o;
  o[0] = f2bf(a.x); o[1] = f2bf(a.y); o[2] = f2bf(a.z); o[3] = f2bf(a.w);
  o[4] = f2bf(b.x); o[5] = f2bf(b.y); o[6] = f2bf(b.z); o[7] = f2bf(b.w);
  *(u16x8*)(out + i) = o;
}

// ---------- pack [w_ih | w_hh] -> wcat[2048][1024] bf16, gate-permuted ----------
// New row nr = cc*128 + wv*16 + OR, where OR&3 = gate, OR>>2 = unit_local(0..3):
// orig grow = (OR&3)*512 + cc*32 + wv*4 + (OR>>2).
// Each lane's MFMA acc[r] = gate r of ONE unit -> lane-local gate math.
__global__ __launch_bounds__(256) void k_pack_w(const float* __restrict__ wih,
                                                const float* __restrict__ whh,
                                                unsigned short* __restrict__ wcat) {
  long i = ((long)blockIdx.x * 256 + threadIdx.x) * 8;
  int nr = (int)(i >> 10), col = (int)(i & 1023);
  int cc = nr >> 7, wvp = (nr >> 4) & 7, OR = nr & 15;
  int grow = (OR & 3) * 512 + cc * 32 + wvp * 4 + (OR >> 2);
  const float* src = (col < 512) ? (wih + (long)grow * 512 + col)
                                 : (whh + (long)grow * 512 + (col - 512));
  const float4* p = (const float4*)src;
  float4 a = p[0], b = p[1];
  u16x8 o;
  o[0] = f2bf(a.x); o[1] = f2bf(a.y); o[2] = f2bf(a.z); o[3] = f2bf(a.w);
  o[4] = f2bf(b.x); o[5] = f2bf(b.y); o[6] = f2bf(b.z); o[7] = f2bf(b.w);
  *(u16x8*)(wcat + i) = o;
}

// ---------- persistent LSTM recurrence, fused Wx+Wh, poison-poll sync ----------
// 96 blocks = 6 row-groups (16 seqs) x 16 col-chunks (32 units). Weights in
// registers (af[32] = 128 VGPR). hout is pre-poisoned 0xFFFFFFFF (bf16 NaN pair,
// unreachable: |h|<1). Producers fire-and-forget sc1 dword stores; consumers
// poll their own h words with sc1 dwordx4 loads until != poison. No flags, no
// fences, no store-drain barrier. 2 barriers/step.
struct LBias { const float* bi[3]; const float* bh[3]; };

__global__ __launch_bounds__(512, 1) void lstm_rec(
    const unsigned short* __restrict__ wcat,  // [3][2048][1024] gate-permuted
    const unsigned short* __restrict__ xs,    // [96][512][512]
    LBias bb,
    unsigned short* __restrict__ hout)        // [96][512][512], pre-poisoned
{
  const int r8 = blockIdx.x & 7;
  if (r8 >= 6) return;
  const int rg = r8, cc = blockIdx.x >> 3;
  const int l = rg >> 1, b0 = (rg & 1) * 16;
  const int tid = threadIdx.x, lane = tid & 63, wv = tid >> 6;

  __shared__ unsigned short sXH[16 * 1024];   // [16 seqs][x(512)|h(512)], XOR(row<<4)

  bf16x8 af[32];
  {
    int nr = cc * 128 + wv * 16 + (lane & 15);
    const unsigned short* Wp = wcat + ((long)l * G4_ + nr) * 1024 + ((lane >> 4) << 3);
#pragma unroll
    for (int kf = 0; kf < 32; ++kf) af[kf] = *(const bf16x8*)(Wp + kf * 32);
  }
  const int u = cc * 32 + wv * 4 + (lane >> 4);
  float bias[4];
#pragma unroll
  for (int r = 0; r < 4; ++r) bias[r] = bb.bi[l][r * 512 + u] + bb.bh[l][r * 512 + u];

  // staging geometry
  const int sx = tid >> 5;                    // seq row 0..15
  const int slot = tid & 31;                  // 16B slot
  const int sw = sx << 4;
  const int xoff0 = sx * 2048 + slot * 16, xoff1 = xoff0 + 512;
  const int hoff0 = xoff0 + 1024,           hoff1 = hoff0 + 512;
  const int slot8 = slot * 8;
  const long seqbase = ((long)(l * B_ + b0 + sx)) * L_;

  // MFMA read geometry
  const int srow = lane & 15;
  const int rbm = srow << 11, swm = srow << 4;
  const int kob = (lane >> 4) << 4;

  // h-store geometry (lane-local gates)
  const int hseq = lane & 15;
  const long hrowb = ((long)(l * B_ + b0 + hseq)) * L_;
  const int upair = cc * 16 + wv * 2 + (lane >> 5);

  u16x8 xr0, xr1;
  {
    const unsigned short* p = xs + seqbase * 512 + slot8;
    xr0 = *(const u16x8*)p;
    xr1 = *(const u16x8*)(p + 256);
  }
  float creg = 0.f;

  for (int t = 0; t < L_; ++t) {
    // stage x(t) into x-half
    *(u16x8*)((char*)sXH + (xoff0 ^ sw)) = xr0;
    *(u16x8*)((char*)sXH + (xoff1 ^ sw)) = xr1;
    if (t + 1 < L_) {
      const unsigned short* p = xs + (seqbase + t + 1) * 512 + slot8;
      xr0 = *(const u16x8*)p;
      xr1 = *(const u16x8*)(p + 256);
    }
    __syncthreads();                          // A: x staged

    // speculative h(t-1) loads (IF-direct), issued before x-MFMAs
    u32x4 h0 = (u32x4){0, 0, 0, 0}, h1 = (u32x4){0, 0, 0, 0};
    const unsigned short* hp0 = hout + (seqbase + t - 1) * 512 + slot8;
    const unsigned short* hp1 = hp0 + 256;
    if (t > 0) {
      asm volatile("global_load_dwordx4 %0, %2, off sc1\n\t"
                   "global_load_dwordx4 %1, %3, off sc1"
                   : "=&v"(h0), "=&v"(h1) : "v"(hp0), "v"(hp1) : "memory");
    }

    // x-half MFMAs (kf 0..15), two accumulator chains
    f32x4 aA = (f32x4){0.f, 0.f, 0.f, 0.f};
    f32x4 aB = (f32x4){0.f, 0.f, 0.f, 0.f};
#pragma unroll
    for (int kf = 0; kf < 16; kf += 2) {
      bf16x8 bv0 = *(const bf16x8*)((const char*)sXH + ((rbm + kf * 64 + kob) ^ swm));
      bf16x8 bv1 = *(const bf16x8*)((const char*)sXH + ((rbm + (kf + 1) * 64 + kob) ^ swm));
      aA = __builtin_amdgcn_mfma_f32_16x16x32_bf16(af[kf], bv0, aA, 0, 0, 0);
      aB = __builtin_amdgcn_mfma_f32_16x16x32_bf16(af[kf + 1], bv1, aB, 0, 0, 0);
    }

    // poison-poll: loop until all 8 words are real data
    if (t > 0) {
      asm volatile("s_waitcnt vmcnt(0)" ::: "memory");
      __builtin_amdgcn_sched_barrier(0);
      while (h0[0] == POI || h0[1] == POI || h0[2] == POI || h0[3] == POI ||
             h1[0] == POI || h1[1] == POI || h1[2] == POI || h1[3] == POI) {
        asm volatile("global_load_dwordx4 %0, %2, off sc1\n\t"
                     "global_load_dwordx4 %1, %3, off sc1\n\t"
                     "s_waitcnt vmcnt(0)"
                     : "=&v"(h0), "=&v"(h1) : "v"(hp0), "v"(hp1) : "memory");
        __builtin_amdgcn_sched_barrier(0);
      }
    }
    // land h into h-half
    *(u16x8*)((char*)sXH + (hoff0 ^ sw)) = *(u16x8*)&h0;
    *(u16x8*)((char*)sXH + (hoff1 ^ sw)) = *(u16x8*)&h1;
    __syncthreads();                          // B: h staged

    // h-half MFMAs (kf 16..31)
#pragma unroll
    for (int kf = 16; kf < 32; kf += 2) {
      bf16x8 bv0 = *(const bf16x8*)((const char*)sXH + ((rbm + kf * 64 + kob) ^ swm));
      bf16x8 bv1 = *(const bf16x8*)((const char*)sXH + ((rbm + (kf + 1) * 64 + kob) ^ swm));
      aA = __builtin_amdgcn_mfma_f32_16x16x32_bf16(af[kf], bv0, aA, 0, 0, 0);
      aB = __builtin_amdgcn_mfma_f32_16x16x32_bf16(af[kf + 1], bv1, aB, 0, 0, 0);
    }

    // lane-local gates; fire-and-forget h store (sc1 -> IF)
    {
      float Pi = aA[0] + aB[0] + bias[0];
      float Pf = aA[1] + aB[1] + bias[1];
      float Pg = aA[2] + aB[2] + bias[2];
      float Po = aA[3] + aB[3] + bias[3];
      float iv = sigf(Pi), fv = sigf(Pf), gv = tanhf_(Pg), ov = sigf(Po);
      creg = fv * creg + iv * gv;
      float h = ov * tanhf_(creg);
      unsigned int hb16 = (unsigned int)f2bf(h);
      unsigned int other = (unsigned int)__shfl_xor((int)hb16, 16);
      if ((lane & 16) == 0) {
        unsigned int pk = hb16 | (other << 16);
        unsigned int* dst = (unsigned int*)(hout + (hrowb + t) * 512) + upair;
        __hip_atomic_store(dst, pk, __ATOMIC_RELAXED, __HIP_MEMORY_SCOPE_AGENT);
      }
    }
  }
}

// ---------- fp32 flash attention (exact), bf16 in/out ----------
__global__ __launch_bounds__(256) void attn_kernel(
    const unsigned short* __restrict__ h, unsigned short* __restrict__ attnout)
{
  const int qt = blockIdx.x, head = blockIdx.y, b = blockIdx.z;
  const int tid = threadIdx.x;

  __shared__ float q_lds[64 * 68];
  __shared__ float ks_lds[64 * 68];
  __shared__ float v_lds[64 * 68];
  __shared__ float corr_lds[64];
  __shared__ float lsum_lds[64];

  const long qbase = ((long)b * L_) * 512;
  const long kbase = ((long)(B_ + b) * L_) * 512;
  const long vbase = ((long)(2 * B_ + b) * L_) * 512;

#pragma unroll
  for (int p = 0; p < 2; ++p) {
    int idx = p * 256 + tid;
    int row = idx >> 3, c8 = (idx & 7) << 3;
    u16x8 v8 = *(const u16x8*)(h + qbase + (long)(qt * 64 + row) * 512 + head * 64 + c8);
#pragma unroll
    for (int j = 0; j < 8; ++j) q_lds[row * 68 + c8 + j] = bf2f(v8[j]);
  }
  float m_run = -1e30f, lsum = 0.f;
  float acc[16];
#pragma unroll
  for (int j = 0; j < 16; ++j) acc[j] = 0.f;
  const int tq = tid & 15, tk = tid >> 4;
  const int oq = tid >> 2, od = (tid & 3) * 16;

  for (int kt = 0; kt < 8; ++kt) {
    __syncthreads();
#pragma unroll
    for (int p = 0; p < 2; ++p) {
      int idx = p * 256 + tid;
      int row = idx >> 3, c8 = (idx & 7) << 3;
      u16x8 kv = *(const u16x8*)(h + kbase + (long)(kt * 64 + row) * 512 + head * 64 + c8);
      u16x8 vv = *(const u16x8*)(h + vbase + (long)(kt * 64 + row) * 512 + head * 64 + c8);
#pragma unroll
      for (int j = 0; j < 8; ++j) {
        ks_lds[row * 68 + c8 + j] = bf2f(kv[j]);
        v_lds[row * 68 + c8 + j]  = bf2f(vv[j]);
      }
    }
    __syncthreads();
    float sc[16];
#pragma unroll
    for (int x = 0; x < 16; ++x) sc[x] = 0.f;
    for (int d4 = 0; d4 < 64; d4 += 4) {
      f32x4 qv[4], kv4[4];
#pragma unroll
      for (int a = 0; a < 4; ++a) qv[a] = *(const f32x4*)&q_lds[(tq + a * 16) * 68 + d4];
#pragma unroll
      for (int c = 0; c < 4; ++c) kv4[c] = *(const f32x4*)&ks_lds[(tk + c * 16) * 68 + d4];
#pragma unroll
      for (int a = 0; a < 4; ++a)
#pragma unroll
        for (int c = 0; c < 4; ++c)
          sc[a * 4 + c] += qv[a][0] * kv4[c][0] + qv[a][1] * kv4[c][1] +
                           qv[a][2] * kv4[c][2] + qv[a][3] * kv4[c][3];
    }
    __syncthreads();
#pragma unroll
    for (int a = 0; a < 4; ++a)
#pragma unroll
      for (int c = 0; c < 4; ++c)
        ks_lds[(tq + a * 16) * 68 + (tk + c * 16)] = sc[a * 4 + c] * 0.125f;
    __syncthreads();
    if (tid < 64) {
      int q = tid;
      float mx = m_run;
      for (int k = 0; k < 64; ++k) mx = fmaxf(mx, ks_lds[q * 68 + k]);
      float corr = __expf(m_run - mx);
      float rs = 0.f;
      for (int k = 0; k < 64; ++k) {
        float p = __expf(ks_lds[q * 68 + k] - mx);
        ks_lds[q * 68 + k] = p;
        rs += p;
      }
      lsum = lsum * corr + rs;
      m_run = mx;
      corr_lds[q] = corr;
    }
    __syncthreads();
    {
      float cr = corr_lds[oq];
#pragma unroll
      for (int j = 0; j < 16; ++j) acc[j] *= cr;
      for (int k = 0; k < 64; ++k) {
        float p = ks_lds[oq * 68 + k];
        f32x4 v0 = *(const f32x4*)&v_lds[k * 68 + od];
        f32x4 v1 = *(const f32x4*)&v_lds[k * 68 + od + 4];
        f32x4 v2 = *(const f32x4*)&v_lds[k * 68 + od + 8];
        f32x4 v3 = *(const f32x4*)&v_lds[k * 68 + od + 12];
#pragma unroll
        for (int j = 0; j < 4; ++j) {
          acc[j]      += p * v0[j];
          acc[4 + j]  += p * v1[j];
          acc[8 + j]  += p * v2[j];
          acc[12 + j] += p * v3[j];
        }
      }
    }
  }
  if (tid < 64) lsum_lds[tid] = lsum;
  __syncthreads();
  float inv = 1.0f / lsum_lds[oq];
  unsigned short* op = attnout + ((long)(b * L_ + qt * 64 + oq)) * 512 + head * 64 + od;
#pragma unroll
  for (int j = 0; j < 16; ++j) op[j] = f2bf(acc[j] * inv);
}

// ---------- projection GEMM: C[16384,512] = A[16384,512]·B[512,512]^T + bias ----------
__global__ __launch_bounds__(256) void gemm_proj(
    const unsigned short* __restrict__ A, const unsigned short* __restrict__ Bw,
    const float* __restrict__ bias, float* __restrict__ C)
{
  const int m0 = blockIdx.y * 128, n0 = blockIdx.x * 128;
  __shared__ unsigned short sA[128 * 64];
  __shared__ unsigned short sB[128 * 64];
  const int tid = threadIdx.x, lane = tid & 63, wv = tid >> 6;
  const int wr = wv >> 1, wc = wv & 1;
  f32x4 acc[4][4];
#pragma unroll
  for (int i = 0; i < 4; ++i)
#pragma unroll
    for (int j = 0; j < 4; ++j) acc[i][j] = (f32x4){0.f, 0.f, 0.f, 0.f};

  for (int kt = 0; kt < 512; kt += 64) {
#pragma unroll
    for (int p = 0; p < 4; ++p) {
      int g = p * 256 + tid;
      int r = g >> 3, c8 = (g & 7) << 3;
      int bo = ((r << 7) + (c8 << 1)) ^ ((r & 7) << 4);
      *(u16x8*)((char*)sA + bo) = *(const u16x8*)(A + (long)(m0 + r) * 512 + kt + c8);
      *(u16x8*)((char*)sB + bo) = *(const u16x8*)(Bw + (long)(n0 + r) * 512 + kt + c8);
    }
    __syncthreads();
#pragma unroll
    for (int kf = 0; kf < 2; ++kf) {
      int cb = kf * 32 + ((lane >> 4) << 3);
      bf16x8 av[4], bv[4];
#pragma unroll
      for (int i = 0; i < 4; ++i) {
        int ra = wr * 64 + i * 16 + (lane & 15);
        av[i] = *(const bf16x8*)((const char*)sA + (((ra << 7) + (cb << 1)) ^ ((ra & 7) << 4)));
        int rb = wc * 64 + i * 16 + (lane & 15);
        bv[i] = *(const bf16x8*)((const char*)sB + (((rb << 7) + (cb << 1)) ^ ((rb & 7) << 4)));
      }
#pragma unroll
      for (int i = 0; i < 4; ++i)
#pragma unroll
        for (int j = 0; j < 4; ++j)
          acc[i][j] = __builtin_amdgcn_mfma_f32_16x16x32_bf16(av[i], bv[j], acc[i][j], 0, 0, 0);
    }
    __syncthreads();
  }
#pragma unroll
  for (int i = 0; i < 4; ++i) {
    int gm0 = m0 + wr * 64 + i * 16 + ((lane >> 4) << 2);
#pragma unroll
    for (int j = 0; j < 4; ++j) {
      int gn = n0 + wc * 64 + j * 16 + (lane & 15);
      float bv = bias[gn];
#pragma unroll
      for (int r = 0; r < 4; ++r)
        C[(long)(gm0 + r) * 512 + gn] = acc[i][j][r] + bv;
    }
  }
}

// ---------- host ----------
extern "C" void kernel_launch(void* const* d_in, const int* in_sizes, int n_in,
                              void* d_out, int out_size, void* d_ws, size_t ws_size,
                              hipStream_t stream)
{
  const float* xin[3]  = {(const float*)d_in[0], (const float*)d_in[1], (const float*)d_in[2]};
  const float* w_ih[3] = {(const float*)d_in[3], (const float*)d_in[7],  (const float*)d_in[11]};
  const float* w_hh[3] = {(const float*)d_in[4], (const float*)d_in[8],  (const float*)d_in[12]};
  const float* b_ih[3] = {(const float*)d_in[5], (const float*)d_in[9],  (const float*)d_in[13]};
  const float* b_hh[3] = {(const float*)d_in[6], (const float*)d_in[10], (const float*)d_in[14]};
  const float* w_out = (const float*)d_in[15];
  const float* b_out = (const float*)d_in[16];

  const size_t TOTAL = 130553856ULL;
  if (ws_size < TOTAL) {
    k_fill<<<dim3(1024), dim3(256), 0, stream>>>((float*)d_out, (long)out_size, 1.0f);
    return;
  }
  char* ws = (char*)d_ws;
  unsigned short* xs      = (unsigned short*)(ws);
  unsigned short* hout    = (unsigned short*)(ws + 50331648);
  unsigned short* wcat    = (unsigned short*)(ws + 100663296);
  unsigned short* wouts   = (unsigned short*)(ws + 113246208);
  unsigned short* attnout = (unsigned short*)(ws + 113770496);

  // pre-poison hout (0xFF bytes = bf16 NaN pairs, unreachable as real h)
  hipMemsetAsync(hout, 0xFF, 50331648, stream);

  for (int l = 0; l < 3; ++l) {
    k_cvt<<<dim3(4096), dim3(256), 0, stream>>>(xin[l], xs + (long)l * 8388608, 8388608L);
    k_pack_w<<<dim3(1024), dim3(256), 0, stream>>>(w_ih[l], w_hh[l], wcat + (long)l * 2097152);
  }
  k_cvt<<<dim3(128), dim3(256), 0, stream>>>(w_out, wouts, 262144L);

  LBias bb;
  for (int l = 0; l < 3; ++l) { bb.bi[l] = b_ih[l]; bb.bh[l] = b_hh[l]; }
  lstm_rec<<<dim3(128), dim3(512), 0, stream>>>(wcat, xs, bb, hout);

  attn_kernel<<<dim3(8, 8, 32), dim3(256), 0, stream>>>(hout, attnout);

  gemm_proj<<<dim3(4, 128), dim3(256), 0, stream>>>(attnout, wouts, b_out, (float*)d_out);
}